// Round 1
// baseline (1064.006 us; speedup 1.0000x reference)
//
#include <hip/hip_runtime.h>
#include <math.h>

static inline int ceil_div(int a, int b) { return (a + b - 1) / b; }

// ---------------------------------------------------------------------------
// Setup kernels: CSR build + weight packing
// ---------------------------------------------------------------------------

__global__ __launch_bounds__(256) void hist_kernel(const int* __restrict__ dst,
                                                   int* __restrict__ deg, int E) {
    int e = blockIdx.x * 256 + threadIdx.x;
    if (e < E) atomicAdd(&deg[dst[e]], 1);
}

__global__ __launch_bounds__(1024) void scan_build(const int* __restrict__ deg,
                                                   int* __restrict__ rowp,
                                                   float* __restrict__ invd,
                                                   int n, int E) {
    __shared__ int sums[1024];
    int t = threadIdx.x;
    int chunk = (n + 1023) >> 10;
    int start = t * chunk;
    int end = start + chunk; if (end > n) end = n;
    int s = 0;
    for (int i = start; i < end; ++i) s += deg[i];
    sums[t] = s;
    __syncthreads();
    for (int off = 1; off < 1024; off <<= 1) {
        int add = (t >= off) ? sums[t - off] : 0;
        __syncthreads();
        sums[t] += add;
        __syncthreads();
    }
    int run = sums[t] - s;  // exclusive prefix for this thread's chunk
    for (int i = start; i < end; ++i) {
        rowp[i] = run;
        int d = deg[i];
        run += d;
        invd[i] = 1.0f / (float)(d > 1 ? d : 1);
    }
    if (t == 0) rowp[n] = E;
}

__global__ __launch_bounds__(256) void scatter_kernel(const int* __restrict__ src,
                                                      const int* __restrict__ dst,
                                                      const float* __restrict__ p,
                                                      const int* __restrict__ rowp,
                                                      int* __restrict__ fill,
                                                      int* __restrict__ es,
                                                      float* __restrict__ ep, int E) {
    int e = blockIdx.x * 256 + threadIdx.x;
    if (e >= E) return;
    int d = dst[e];
    int pos = rowp[d] + atomicAdd(&fill[d], 1);
    es[pos] = src[e];
    ep[pos] = p[e];
}

// pack [2,K,C] W + [K,C] R into row-major [K, 3C] = [W0 | W1 | R]
__global__ __launch_bounds__(256) void pack_cat3(const float* __restrict__ W,
                                                 const float* __restrict__ R,
                                                 float* __restrict__ out, int K, int C) {
    int idx = blockIdx.x * 256 + threadIdx.x;
    int M = 3 * C;
    if (idx >= K * M) return;
    int k = idx / M, c = idx % M;
    float v;
    if (c < C)            v = W[k * C + c];
    else if (c < 2 * C)   v = W[K * C + k * C + (c - C)];
    else                  v = R[k * C + (c - 2 * C)];
    out[idx] = v;
}

// ---------------------------------------------------------------------------
// Edge-aggregation kernels (CSR, wave-per-node, lane-per-channel)
// ---------------------------------------------------------------------------

// Aggregate-first (hidden convs, C=64): agg[i] = [sum (1-p) x_src | sum p x_src] * inv_deg
__global__ __launch_bounds__(256) void edge_agg64(const float* __restrict__ x,
                                                  const int* __restrict__ rowp,
                                                  const int* __restrict__ es,
                                                  const float* __restrict__ ep,
                                                  const float* __restrict__ invd,
                                                  float* __restrict__ agg, int n) {
    int gid = blockIdx.x * 256 + threadIdx.x;
    int node = gid >> 6;
    if (node >= n) return;
    int c = gid & 63;
    int e = rowp[node], eend = rowp[node + 1];
    float asum = 0.f, ap = 0.f;
    for (; e + 4 <= eend; e += 4) {
        int s0 = es[e], s1 = es[e + 1], s2 = es[e + 2], s3 = es[e + 3];
        float p0 = ep[e], p1 = ep[e + 1], p2 = ep[e + 2], p3 = ep[e + 3];
        float v0 = x[(size_t)s0 * 64 + c];
        float v1 = x[(size_t)s1 * 64 + c];
        float v2 = x[(size_t)s2 * 64 + c];
        float v3 = x[(size_t)s3 * 64 + c];
        asum += (v0 + v1) + (v2 + v3);
        ap = fmaf(p0, v0, fmaf(p1, v1, fmaf(p2, v2, fmaf(p3, v3, ap))));
    }
    for (; e < eend; ++e) {
        int s = es[e]; float pe = ep[e];
        float v = x[(size_t)s * 64 + c];
        asum += v; ap = fmaf(pe, v, ap);
    }
    float w = invd[node];
    agg[(size_t)node * 128 + c]      = (asum - ap) * w;
    agg[(size_t)node * 128 + 64 + c] = ap * w;
}

// Transform-first (conv1, C=64): out = tanh(agg((1-p)y+p z)*inv + base)
__global__ __launch_bounds__(256) void edge_tf64(const float* __restrict__ yz,
                                                 const int* __restrict__ rowp,
                                                 const int* __restrict__ es,
                                                 const float* __restrict__ ep,
                                                 const float* __restrict__ invd,
                                                 const float* __restrict__ base,
                                                 float* __restrict__ out, int n) {
    int gid = blockIdx.x * 256 + threadIdx.x;
    int node = gid >> 6;
    if (node >= n) return;
    int c = gid & 63;
    int e = rowp[node], eend = rowp[node + 1];
    float a = 0.f;
    for (; e + 4 <= eend; e += 4) {
        int s0 = es[e], s1 = es[e + 1], s2 = es[e + 2], s3 = es[e + 3];
        float p0 = ep[e], p1 = ep[e + 1], p2 = ep[e + 2], p3 = ep[e + 3];
        float y0 = yz[(size_t)s0 * 128 + c],      z0 = yz[(size_t)s0 * 128 + 64 + c];
        float y1 = yz[(size_t)s1 * 128 + c],      z1 = yz[(size_t)s1 * 128 + 64 + c];
        float y2 = yz[(size_t)s2 * 128 + c],      z2 = yz[(size_t)s2 * 128 + 64 + c];
        float y3 = yz[(size_t)s3 * 128 + c],      z3 = yz[(size_t)s3 * 128 + 64 + c];
        a += fmaf(p0, z0 - y0, y0);
        a += fmaf(p1, z1 - y1, y1);
        a += fmaf(p2, z2 - y2, y2);
        a += fmaf(p3, z3 - y3, y3);
    }
    for (; e < eend; ++e) {
        int s = es[e]; float pe = ep[e];
        float y = yz[(size_t)s * 128 + c], z = yz[(size_t)s * 128 + 64 + c];
        a += fmaf(pe, z - y, y);
    }
    size_t idx = (size_t)node * 64 + c;
    out[idx] = tanhf(a * invd[node] + base[idx]);
}

// Transform-first conv2 (C=16) + fused tanh + log_softmax over the 16 lanes
__global__ __launch_bounds__(256) void edge_tf16_lsm(const float* __restrict__ yz,
                                                     const int* __restrict__ rowp,
                                                     const int* __restrict__ es,
                                                     const float* __restrict__ ep,
                                                     const float* __restrict__ invd,
                                                     const float* __restrict__ base,
                                                     float* __restrict__ out, int n) {
    int gid = blockIdx.x * 256 + threadIdx.x;
    int node = gid >> 4;
    if (node >= n) return;
    int c = gid & 15;
    int e = rowp[node], eend = rowp[node + 1];
    float a = 0.f;
    for (; e + 4 <= eend; e += 4) {
        int s0 = es[e], s1 = es[e + 1], s2 = es[e + 2], s3 = es[e + 3];
        float p0 = ep[e], p1 = ep[e + 1], p2 = ep[e + 2], p3 = ep[e + 3];
        float y0 = yz[(size_t)s0 * 32 + c],      z0 = yz[(size_t)s0 * 32 + 16 + c];
        float y1 = yz[(size_t)s1 * 32 + c],      z1 = yz[(size_t)s1 * 32 + 16 + c];
        float y2 = yz[(size_t)s2 * 32 + c],      z2 = yz[(size_t)s2 * 32 + 16 + c];
        float y3 = yz[(size_t)s3 * 32 + c],      z3 = yz[(size_t)s3 * 32 + 16 + c];
        a += fmaf(p0, z0 - y0, y0);
        a += fmaf(p1, z1 - y1, y1);
        a += fmaf(p2, z2 - y2, y2);
        a += fmaf(p3, z3 - y3, y3);
    }
    for (; e < eend; ++e) {
        int s = es[e]; float pe = ep[e];
        float y = yz[(size_t)s * 32 + c], z = yz[(size_t)s * 32 + 16 + c];
        a += fmaf(pe, z - y, y);
    }
    float o = tanhf(a * invd[node] + base[(size_t)node * 16 + c]);
    // log_softmax across the 16 lanes of this node group
    float m = o;
    #pragma unroll
    for (int off = 8; off >= 1; off >>= 1) m = fmaxf(m, __shfl_xor(m, off, 16));
    float ex = expf(o - m);
    float s = ex;
    #pragma unroll
    for (int off = 8; off >= 1; off >>= 1) s += __shfl_xor(s, off, 16);
    out[(size_t)node * 16 + c] = (o - m) - logf(s);
}

// ---------------------------------------------------------------------------
// Generic fp32 GEMM: C[n,M] = A[n,K] @ B[K,M], A possibly split into two
// row-segments along K (A0: k<K0, A1: k>=K0). Epilogue modes:
//   mode 0: two column regions [0,split) -> out0 (+bias0), [split,M) -> out1 (+bias1)
//   mode 1: RK epilogue (M==64): v=acc+bias0; an=acc_in+c3*v; acc_out=an;
//           t_out = h + c1*v + c2*an
// ---------------------------------------------------------------------------
__global__ __launch_bounds__(256) void gemm_tiled(
    const float* __restrict__ A0, int lda0, int K0,
    const float* __restrict__ A1, int lda1,
    const float* __restrict__ B,
    int n, int K, int M,
    float* __restrict__ out0, int w0, const float* __restrict__ bias0,
    float* __restrict__ out1, int w1, const float* __restrict__ bias1,
    int split, int mode,
    const float* __restrict__ hbuf, const float* __restrict__ acc_in,
    float* __restrict__ acc_out, float* __restrict__ t_out,
    float c1, float c2, float c3) {
    __shared__ __align__(16) float As[16][68];
    __shared__ __align__(16) float Bs[16][68];
    const int t = threadIdx.x;
    const int row0 = blockIdx.x * 64;
    const int col0 = blockIdx.y * 64;
    const int ty = t >> 4, tx = t & 15;
    const int lrow = t >> 2, lk = (t & 3) << 2;
    const int bkk = t >> 4, bcol = (t & 15) << 2;
    float acc[4][4];
    #pragma unroll
    for (int i = 0; i < 4; ++i)
        #pragma unroll
        for (int j = 0; j < 4; ++j) acc[i][j] = 0.f;

    for (int k0 = 0; k0 < K; k0 += 16) {
        float4 av = make_float4(0.f, 0.f, 0.f, 0.f);
        {
            int r = row0 + lrow;
            if (r < n) {
                int kk = k0 + lk;
                const float* src = (kk < K0)
                    ? (A0 + (size_t)r * lda0 + kk)
                    : (A1 + (size_t)r * lda1 + (kk - K0));
                av = *reinterpret_cast<const float4*>(src);
            }
        }
        float4 bv = make_float4(0.f, 0.f, 0.f, 0.f);
        {
            int c = col0 + bcol;
            int kk = k0 + bkk;
            if (c < M) bv = *reinterpret_cast<const float4*>(B + (size_t)kk * M + c);
        }
        As[lk + 0][lrow] = av.x; As[lk + 1][lrow] = av.y;
        As[lk + 2][lrow] = av.z; As[lk + 3][lrow] = av.w;
        *reinterpret_cast<float4*>(&Bs[bkk][bcol]) = bv;
        __syncthreads();
        #pragma unroll
        for (int kk = 0; kk < 16; ++kk) {
            float4 a4 = *reinterpret_cast<const float4*>(&As[kk][ty << 2]);
            float4 b4 = *reinterpret_cast<const float4*>(&Bs[kk][tx << 2]);
            float aa[4] = {a4.x, a4.y, a4.z, a4.w};
            float bb[4] = {b4.x, b4.y, b4.z, b4.w};
            #pragma unroll
            for (int i = 0; i < 4; ++i)
                #pragma unroll
                for (int j = 0; j < 4; ++j)
                    acc[i][j] = fmaf(aa[i], bb[j], acc[i][j]);
        }
        __syncthreads();
    }

    #pragma unroll
    for (int i = 0; i < 4; ++i) {
        int r = row0 + (ty << 2) + i;
        if (r >= n) continue;
        #pragma unroll
        for (int j = 0; j < 4; ++j) {
            int c = col0 + (tx << 2) + j;
            if (c >= M) continue;
            float v = acc[i][j];
            if (mode == 0) {
                if (c < split) {
                    if (bias0) v += bias0[c];
                    out0[(size_t)r * w0 + c] = v;
                } else {
                    int cc = c - split;
                    if (bias1) v += bias1[cc];
                    out1[(size_t)r * w1 + cc] = v;
                }
            } else {
                if (bias0) v += bias0[c];
                size_t idx = (size_t)r * 64 + c;
                float an = (acc_in ? acc_in[idx] : 0.f) + c3 * v;
                acc_out[idx] = an;
                t_out[idx] = hbuf[idx] + c1 * v + c2 * an;
            }
        }
    }
}

// ---------------------------------------------------------------------------
// Host-side launcher
// ---------------------------------------------------------------------------

static void hidden_conv(hipStream_t stream, const float* in, float* big0,
                        const int* rowp, const int* es, const float* ep,
                        const float* invd, const float* Bc, const float* bias, int n,
                        int mode, float* out_plain,
                        const float* h, const float* acc_in, float* acc_out,
                        float* t_out, float c1, float c2, float c3) {
    edge_agg64<<<ceil_div(n * 64, 256), 256, 0, stream>>>(in, rowp, es, ep, invd, big0, n);
    dim3 g(ceil_div(n, 64), 1);
    gemm_tiled<<<g, 256, 0, stream>>>(big0, 128, 128, in, 64, Bc, n, 192, 64,
                                      out_plain, 64, bias, nullptr, 0, nullptr, 64, mode,
                                      h, acc_in, acc_out, t_out, c1, c2, c3);
}

extern "C" void kernel_launch(void* const* d_in, const int* in_sizes, int n_in,
                              void* d_out, int out_size, void* d_ws, size_t ws_size,
                              hipStream_t stream) {
    const float* x  = (const float*)d_in[0];
    const float* pE = (const float*)d_in[1];
    const int*   sr = (const int*)d_in[2];
    const int*   ds = (const int*)d_in[3];
    const float* W1 = (const float*)d_in[4];
    const float* R1 = (const float*)d_in[5];
    const float* b1 = (const float*)d_in[6];
    const float* Wa = (const float*)d_in[7];
    const float* Ra = (const float*)d_in[8];
    const float* ba = (const float*)d_in[9];
    const float* Wb = (const float*)d_in[10];
    const float* Rb = (const float*)d_in[11];
    const float* bb = (const float*)d_in[12];
    const float* W2 = (const float*)d_in[13];
    const float* R2 = (const float*)d_in[14];
    const float* b2 = (const float*)d_in[15];
    const int n = in_sizes[0] / 256;
    const int E = in_sizes[2];
    float* out = (float*)d_out;

    char* w = (char*)d_ws;
    auto alloc = [&](size_t bytes) -> void* {
        void* ptr = (void*)w;
        w += (bytes + 255) & ~(size_t)255;
        return ptr;
    };
    int*   deg  = (int*)alloc((size_t)n * 4);
    int*   fill = (int*)alloc((size_t)n * 4);
    int*   rowp = (int*)alloc((size_t)(n + 1) * 4);
    float* invd = (float*)alloc((size_t)n * 4);
    int*   es   = (int*)alloc((size_t)E * 4);
    float* ep   = (float*)alloc((size_t)E * 4);
    float* Bc1  = (float*)alloc((size_t)256 * 192 * 4);
    float* Bca  = (float*)alloc((size_t)192 * 64 * 4);
    float* Bcb  = (float*)alloc((size_t)192 * 64 * 4);
    float* Bc2  = (float*)alloc((size_t)64 * 48 * 4);
    float* big0 = (float*)alloc((size_t)n * 128 * 4);  // yz / agg buffer
    float* big1 = (float*)alloc((size_t)n * 64 * 4);   // base buffer
    float* h    = (float*)alloc((size_t)n * 64 * 4);
    float* u    = (float*)alloc((size_t)n * 64 * 4);
    float* tb   = (float*)alloc((size_t)n * 64 * 4);
    float* acc  = (float*)alloc((size_t)n * 64 * 4);

    hipMemsetAsync(deg, 0, (size_t)n * 4, stream);
    hipMemsetAsync(fill, 0, (size_t)n * 4, stream);

    pack_cat3<<<ceil_div(256 * 192, 256), 256, 0, stream>>>(W1, R1, Bc1, 256, 64);
    pack_cat3<<<ceil_div(64 * 48, 256), 256, 0, stream>>>(W2, R2, Bc2, 64, 16);
    hipMemcpyAsync(Bca, Wa, (size_t)8192 * 4, hipMemcpyDeviceToDevice, stream);
    hipMemcpyAsync(Bca + 8192, Ra, (size_t)4096 * 4, hipMemcpyDeviceToDevice, stream);
    hipMemcpyAsync(Bcb, Wb, (size_t)8192 * 4, hipMemcpyDeviceToDevice, stream);
    hipMemcpyAsync(Bcb + 8192, Rb, (size_t)4096 * 4, hipMemcpyDeviceToDevice, stream);

    hist_kernel<<<ceil_div(E, 256), 256, 0, stream>>>(ds, deg, E);
    scan_build<<<1, 1024, 0, stream>>>(deg, rowp, invd, n, E);
    scatter_kernel<<<ceil_div(E, 256), 256, 0, stream>>>(sr, ds, pE, rowp, fill, es, ep, E);

    // conv1: transform-first. GEMM x@[W1_0|W1_1|R1] -> yz(big0), base(big1)+b1
    {
        dim3 g(ceil_div(n, 64), 3);
        gemm_tiled<<<g, 256, 0, stream>>>(x, 256, 256, nullptr, 0, Bc1, n, 256, 192,
                                          big0, 128, nullptr, big1, 64, b1, 128, 0,
                                          nullptr, nullptr, nullptr, nullptr, 0.f, 0.f, 0.f);
        edge_tf64<<<ceil_div(n * 64, 256), 256, 0, stream>>>(big0, rowp, es, ep, invd,
                                                             big1, h, n);
    }

    // RK4 over f(y) = conv_b(conv_a(y)), T=3
    // k1
    hidden_conv(stream, h, big0, rowp, es, ep, invd, Bca, ba, n, 0, u,
                nullptr, nullptr, nullptr, nullptr, 0.f, 0.f, 0.f);
    hidden_conv(stream, u, big0, rowp, es, ep, invd, Bcb, bb, n, 1, nullptr,
                h, nullptr, acc, tb, 1.5f, 0.f, 1.f);
    // k2
    hidden_conv(stream, tb, big0, rowp, es, ep, invd, Bca, ba, n, 0, u,
                nullptr, nullptr, nullptr, nullptr, 0.f, 0.f, 0.f);
    hidden_conv(stream, u, big0, rowp, es, ep, invd, Bcb, bb, n, 1, nullptr,
                h, acc, acc, tb, 1.5f, 0.f, 2.f);
    // k3
    hidden_conv(stream, tb, big0, rowp, es, ep, invd, Bca, ba, n, 0, u,
                nullptr, nullptr, nullptr, nullptr, 0.f, 0.f, 0.f);
    hidden_conv(stream, u, big0, rowp, es, ep, invd, Bcb, bb, n, 1, nullptr,
                h, acc, acc, tb, 3.f, 0.f, 2.f);
    // k4: t_out becomes h_new = h + 0.5*(k1+2k2+2k3+k4)
    hidden_conv(stream, tb, big0, rowp, es, ep, invd, Bca, ba, n, 0, u,
                nullptr, nullptr, nullptr, nullptr, 0.f, 0.f, 0.f);
    hidden_conv(stream, u, big0, rowp, es, ep, invd, Bcb, bb, n, 1, nullptr,
                h, acc, acc, tb, 0.f, 0.5f, 1.f);

    // conv2: transform-first. GEMM h_new@[W2_0|W2_1|R2] -> yz2(big0,w=32), base2(big1,w=16)+b2
    {
        dim3 g(ceil_div(n, 64), 1);
        gemm_tiled<<<g, 256, 0, stream>>>(tb, 64, 64, nullptr, 0, Bc2, n, 64, 48,
                                          big0, 32, nullptr, big1, 16, b2, 32, 0,
                                          nullptr, nullptr, nullptr, nullptr, 0.f, 0.f, 0.f);
        edge_tf16_lsm<<<ceil_div(n * 16, 256), 256, 0, stream>>>(big0, rowp, es, ep, invd,
                                                                 big1, out, n);
    }
}

// Round 3
// 951.680 us; speedup vs baseline: 1.1180x; 1.1180x over previous
//
#include <hip/hip_runtime.h>
#include <math.h>

static inline int ceil_div(int a, int b) { return (a + b - 1) / b; }

// ---------------------------------------------------------------------------
// Setup kernels: CSR build + weight packing
// ---------------------------------------------------------------------------

__global__ __launch_bounds__(256) void hist_kernel(const int* __restrict__ dst,
                                                   int* __restrict__ deg, int E) {
    int e = blockIdx.x * 256 + threadIdx.x;
    if (e < E) atomicAdd(&deg[dst[e]], 1);
}

// Hierarchical exclusive scan of deg[] -> rowp[], plus invd[].
__global__ __launch_bounds__(256) void scan_blocksum(const int* __restrict__ deg,
                                                     int* __restrict__ bsum, int n) {
    __shared__ int red[256];
    int t = threadIdx.x;
    int base = blockIdx.x * 2048 + t * 8;
    int s = 0;
    #pragma unroll
    for (int i = 0; i < 8; ++i) {
        int idx = base + i;
        if (idx < n) s += deg[idx];
    }
    red[t] = s;
    __syncthreads();
    #pragma unroll
    for (int off = 128; off >= 1; off >>= 1) {
        if (t < off) red[t] += red[t + off];
        __syncthreads();
    }
    if (t == 0) bsum[blockIdx.x] = red[0];
}

__global__ __launch_bounds__(256) void scan_tops(int* __restrict__ bsum, int nb) {
    __shared__ int sh[256];
    int t = threadIdx.x;
    int orig = (t < nb) ? bsum[t] : 0;
    sh[t] = orig;
    __syncthreads();
    for (int off = 1; off < 256; off <<= 1) {
        int add = (t >= off) ? sh[t - off] : 0;
        __syncthreads();
        sh[t] += add;
        __syncthreads();
    }
    if (t < nb) bsum[t] = sh[t] - orig;  // exclusive prefix
}

__global__ __launch_bounds__(256) void scan_final(const int* __restrict__ deg,
                                                  const int* __restrict__ bsum,
                                                  int* __restrict__ rowp,
                                                  float* __restrict__ invd,
                                                  int n, int E) {
    __shared__ int sh[256];
    int t = threadIdx.x;
    int base = blockIdx.x * 2048 + t * 8;
    int loc[8];
    int s = 0;
    #pragma unroll
    for (int i = 0; i < 8; ++i) {
        int idx = base + i;
        int d = (idx < n) ? deg[idx] : 0;
        loc[i] = d;
        s += d;
    }
    sh[t] = s;
    __syncthreads();
    for (int off = 1; off < 256; off <<= 1) {
        int add = (t >= off) ? sh[t - off] : 0;
        __syncthreads();
        sh[t] += add;
        __syncthreads();
    }
    int run = bsum[blockIdx.x] + (sh[t] - s);
    #pragma unroll
    for (int i = 0; i < 8; ++i) {
        int idx = base + i;
        if (idx < n) {
            rowp[idx] = run;
            int d = loc[i];
            run += d;
            invd[idx] = 1.0f / (float)(d > 1 ? d : 1);
        }
    }
    if (blockIdx.x == 0 && t == 0) rowp[n] = E;
}

// Scatter EDGE INDICES (nondeterministic intra-node order; fixed by sort_fill).
__global__ __launch_bounds__(256) void scatter_idx(const int* __restrict__ dst,
                                                   const int* __restrict__ rowp,
                                                   int* __restrict__ fill,
                                                   int* __restrict__ ei, int E) {
    int e = blockIdx.x * 256 + threadIdx.x;
    if (e >= E) return;
    int d = dst[e];
    int pos = rowp[d] + atomicAdd(&fill[d], 1);
    ei[pos] = e;
}

// Deterministic order: insertion-sort each node's segment by edge index, then
// materialize es/ep. Avg degree 16 -> ~128 cmps per thread; total work tiny.
// This makes the whole pipeline bitwise run-to-run deterministic (RK4 with
// T=3 amplifies summation-order noise to O(1) — determinism is correctness).
__global__ __launch_bounds__(256) void sort_fill(const int* __restrict__ rowp,
                                                 int* __restrict__ ei,
                                                 const int* __restrict__ src,
                                                 const float* __restrict__ p,
                                                 int* __restrict__ es,
                                                 float* __restrict__ ep, int n) {
    int node = blockIdx.x * 256 + threadIdx.x;
    if (node >= n) return;
    int b = rowp[node], e = rowp[node + 1];
    for (int i = b + 1; i < e; ++i) {
        int key = ei[i];
        int j = i - 1;
        while (j >= b && ei[j] > key) { ei[j + 1] = ei[j]; --j; }
        ei[j + 1] = key;
    }
    for (int i = b; i < e; ++i) {
        int id = ei[i];
        es[i] = src[id];
        ep[i] = p[id];
    }
}

// pack [2,K,C] W + [K,C] R into row-major [K, 3C] = [W0 | W1 | R]
__global__ __launch_bounds__(256) void pack_cat3(const float* __restrict__ W,
                                                 const float* __restrict__ R,
                                                 float* __restrict__ out, int K, int C) {
    int idx = blockIdx.x * 256 + threadIdx.x;
    int M = 3 * C;
    if (idx >= K * M) return;
    int k = idx / M, c = idx % M;
    float v;
    if (c < C)            v = W[k * C + c];
    else if (c < 2 * C)   v = W[K * C + k * C + (c - C)];
    else                  v = R[k * C + (c - 2 * C)];
    out[idx] = v;
}

// ---------------------------------------------------------------------------
// Edge-aggregation kernels (CSR). 16 lanes per node, float4 per lane.
// ---------------------------------------------------------------------------

__global__ __launch_bounds__(256) void edge_agg64_v4(const float* __restrict__ x,
                                                     const int* __restrict__ rowp,
                                                     const int* __restrict__ es,
                                                     const float* __restrict__ ep,
                                                     const float* __restrict__ invd,
                                                     float* __restrict__ agg, int n) {
    int gid = blockIdx.x * 256 + threadIdx.x;
    int node = gid >> 4;
    if (node >= n) return;
    int c4 = (gid & 15) << 2;
    int e = rowp[node], eend = rowp[node + 1];
    float sx = 0.f, sy = 0.f, sz = 0.f, sw = 0.f;
    float px = 0.f, py = 0.f, pz = 0.f, pw = 0.f;
    for (; e + 4 <= eend; e += 4) {
        int s0 = es[e], s1 = es[e + 1], s2 = es[e + 2], s3 = es[e + 3];
        float p0 = ep[e], p1 = ep[e + 1], p2 = ep[e + 2], p3 = ep[e + 3];
        float4 v0 = *reinterpret_cast<const float4*>(&x[(size_t)s0 * 64 + c4]);
        float4 v1 = *reinterpret_cast<const float4*>(&x[(size_t)s1 * 64 + c4]);
        float4 v2 = *reinterpret_cast<const float4*>(&x[(size_t)s2 * 64 + c4]);
        float4 v3 = *reinterpret_cast<const float4*>(&x[(size_t)s3 * 64 + c4]);
        sx += (v0.x + v1.x) + (v2.x + v3.x);
        sy += (v0.y + v1.y) + (v2.y + v3.y);
        sz += (v0.z + v1.z) + (v2.z + v3.z);
        sw += (v0.w + v1.w) + (v2.w + v3.w);
        px = fmaf(p0, v0.x, fmaf(p1, v1.x, fmaf(p2, v2.x, fmaf(p3, v3.x, px))));
        py = fmaf(p0, v0.y, fmaf(p1, v1.y, fmaf(p2, v2.y, fmaf(p3, v3.y, py))));
        pz = fmaf(p0, v0.z, fmaf(p1, v1.z, fmaf(p2, v2.z, fmaf(p3, v3.z, pz))));
        pw = fmaf(p0, v0.w, fmaf(p1, v1.w, fmaf(p2, v2.w, fmaf(p3, v3.w, pw))));
    }
    for (; e < eend; ++e) {
        int s = es[e];
        float pe = ep[e];
        float4 v = *reinterpret_cast<const float4*>(&x[(size_t)s * 64 + c4]);
        sx += v.x; sy += v.y; sz += v.z; sw += v.w;
        px = fmaf(pe, v.x, px); py = fmaf(pe, v.y, py);
        pz = fmaf(pe, v.z, pz); pw = fmaf(pe, v.w, pw);
    }
    float w = invd[node];
    float4 a0 = make_float4((sx - px) * w, (sy - py) * w, (sz - pz) * w, (sw - pw) * w);
    float4 a1 = make_float4(px * w, py * w, pz * w, pw * w);
    *reinterpret_cast<float4*>(&agg[(size_t)node * 128 + c4]) = a0;
    *reinterpret_cast<float4*>(&agg[(size_t)node * 128 + 64 + c4]) = a1;
}

__global__ __launch_bounds__(256) void edge_tf64_v4(const float* __restrict__ yz,
                                                    const int* __restrict__ rowp,
                                                    const int* __restrict__ es,
                                                    const float* __restrict__ ep,
                                                    const float* __restrict__ invd,
                                                    const float* __restrict__ base,
                                                    float* __restrict__ out, int n) {
    int gid = blockIdx.x * 256 + threadIdx.x;
    int node = gid >> 4;
    if (node >= n) return;
    int c4 = (gid & 15) << 2;
    int e = rowp[node], eend = rowp[node + 1];
    float ax = 0.f, ay = 0.f, az = 0.f, aw = 0.f;
    for (; e + 2 <= eend; e += 2) {
        int s0 = es[e], s1 = es[e + 1];
        float p0 = ep[e], p1 = ep[e + 1];
        float4 y0 = *reinterpret_cast<const float4*>(&yz[(size_t)s0 * 128 + c4]);
        float4 z0 = *reinterpret_cast<const float4*>(&yz[(size_t)s0 * 128 + 64 + c4]);
        float4 y1 = *reinterpret_cast<const float4*>(&yz[(size_t)s1 * 128 + c4]);
        float4 z1 = *reinterpret_cast<const float4*>(&yz[(size_t)s1 * 128 + 64 + c4]);
        ax += fmaf(p0, z0.x - y0.x, y0.x) + fmaf(p1, z1.x - y1.x, y1.x);
        ay += fmaf(p0, z0.y - y0.y, y0.y) + fmaf(p1, z1.y - y1.y, y1.y);
        az += fmaf(p0, z0.z - y0.z, y0.z) + fmaf(p1, z1.z - y1.z, y1.z);
        aw += fmaf(p0, z0.w - y0.w, y0.w) + fmaf(p1, z1.w - y1.w, y1.w);
    }
    for (; e < eend; ++e) {
        int s = es[e];
        float pe = ep[e];
        float4 y = *reinterpret_cast<const float4*>(&yz[(size_t)s * 128 + c4]);
        float4 z = *reinterpret_cast<const float4*>(&yz[(size_t)s * 128 + 64 + c4]);
        ax += fmaf(pe, z.x - y.x, y.x);
        ay += fmaf(pe, z.y - y.y, y.y);
        az += fmaf(pe, z.z - y.z, y.z);
        aw += fmaf(pe, z.w - y.w, y.w);
    }
    float w = invd[node];
    size_t idx = (size_t)node * 64 + c4;
    float4 b = *reinterpret_cast<const float4*>(&base[idx]);
    float4 o = make_float4(tanhf(fmaf(ax, w, b.x)), tanhf(fmaf(ay, w, b.y)),
                           tanhf(fmaf(az, w, b.z)), tanhf(fmaf(aw, w, b.w)));
    *reinterpret_cast<float4*>(&out[idx]) = o;
}

__global__ __launch_bounds__(256) void edge_tf16_lsm(const float* __restrict__ yz,
                                                     const int* __restrict__ rowp,
                                                     const int* __restrict__ es,
                                                     const float* __restrict__ ep,
                                                     const float* __restrict__ invd,
                                                     const float* __restrict__ base,
                                                     float* __restrict__ out, int n) {
    int gid = blockIdx.x * 256 + threadIdx.x;
    int node = gid >> 4;
    if (node >= n) return;
    int c = gid & 15;
    int e = rowp[node], eend = rowp[node + 1];
    float a = 0.f;
    for (; e + 4 <= eend; e += 4) {
        int s0 = es[e], s1 = es[e + 1], s2 = es[e + 2], s3 = es[e + 3];
        float p0 = ep[e], p1 = ep[e + 1], p2 = ep[e + 2], p3 = ep[e + 3];
        float y0 = yz[(size_t)s0 * 32 + c],      z0 = yz[(size_t)s0 * 32 + 16 + c];
        float y1 = yz[(size_t)s1 * 32 + c],      z1 = yz[(size_t)s1 * 32 + 16 + c];
        float y2 = yz[(size_t)s2 * 32 + c],      z2 = yz[(size_t)s2 * 32 + 16 + c];
        float y3 = yz[(size_t)s3 * 32 + c],      z3 = yz[(size_t)s3 * 32 + 16 + c];
        a += fmaf(p0, z0 - y0, y0);
        a += fmaf(p1, z1 - y1, y1);
        a += fmaf(p2, z2 - y2, y2);
        a += fmaf(p3, z3 - y3, y3);
    }
    for (; e < eend; ++e) {
        int s = es[e]; float pe = ep[e];
        float y = yz[(size_t)s * 32 + c], z = yz[(size_t)s * 32 + 16 + c];
        a += fmaf(pe, z - y, y);
    }
    float o = tanhf(a * invd[node] + base[(size_t)node * 16 + c]);
    float m = o;
    #pragma unroll
    for (int off = 8; off >= 1; off >>= 1) m = fmaxf(m, __shfl_xor(m, off, 16));
    float ex = expf(o - m);
    float s = ex;
    #pragma unroll
    for (int off = 8; off >= 1; off >>= 1) s += __shfl_xor(s, off, 16);
    out[(size_t)node * 16 + c] = (o - m) - logf(s);
}

// ---------------------------------------------------------------------------
// Generic fp32 GEMM: C[n,M] = A[n,K] @ B[K,M]; A split at K0 (A0/A1).
//   mode 0: cols [0,split)->out0(+bias0), [split,M)->out1(+bias1)
//   mode 1: RK epilogue: v=acc+bias0; an=acc_in+c3*v; acc_out=an;
//           t_out = h + c1*v + c2*an
// ---------------------------------------------------------------------------
__global__ __launch_bounds__(256) void gemm_tiled(
    const float* __restrict__ A0, int lda0, int K0,
    const float* __restrict__ A1, int lda1,
    const float* __restrict__ B,
    int n, int K, int M,
    float* __restrict__ out0, int w0, const float* __restrict__ bias0,
    float* __restrict__ out1, int w1, const float* __restrict__ bias1,
    int split, int mode,
    const float* __restrict__ hbuf, const float* __restrict__ acc_in,
    float* __restrict__ acc_out, float* __restrict__ t_out,
    float c1, float c2, float c3) {
    __shared__ __align__(16) float As[16][68];
    __shared__ __align__(16) float Bs[16][68];
    const int t = threadIdx.x;
    const int row0 = blockIdx.x * 64;
    const int col0 = blockIdx.y * 64;
    const int ty = t >> 4, tx = t & 15;
    const int lrow = t >> 2, lk = (t & 3) << 2;
    const int bkk = t >> 4, bcol = (t & 15) << 2;
    float acc[4][4];
    #pragma unroll
    for (int i = 0; i < 4; ++i)
        #pragma unroll
        for (int j = 0; j < 4; ++j) acc[i][j] = 0.f;

    for (int k0 = 0; k0 < K; k0 += 16) {
        float4 av = make_float4(0.f, 0.f, 0.f, 0.f);
        {
            int r = row0 + lrow;
            if (r < n) {
                int kk = k0 + lk;
                const float* src = (kk < K0)
                    ? (A0 + (size_t)r * lda0 + kk)
                    : (A1 + (size_t)r * lda1 + (kk - K0));
                av = *reinterpret_cast<const float4*>(src);
            }
        }
        float4 bv = make_float4(0.f, 0.f, 0.f, 0.f);
        {
            int c = col0 + bcol;
            int kk = k0 + bkk;
            if (c < M) bv = *reinterpret_cast<const float4*>(B + (size_t)kk * M + c);
        }
        As[lk + 0][lrow] = av.x; As[lk + 1][lrow] = av.y;
        As[lk + 2][lrow] = av.z; As[lk + 3][lrow] = av.w;
        *reinterpret_cast<float4*>(&Bs[bkk][bcol]) = bv;
        __syncthreads();
        #pragma unroll
        for (int kk = 0; kk < 16; ++kk) {
            float4 a4 = *reinterpret_cast<const float4*>(&As[kk][ty << 2]);
            float4 b4 = *reinterpret_cast<const float4*>(&Bs[kk][tx << 2]);
            float aa[4] = {a4.x, a4.y, a4.z, a4.w};
            float bb[4] = {b4.x, b4.y, b4.z, b4.w};
            #pragma unroll
            for (int i = 0; i < 4; ++i)
                #pragma unroll
                for (int j = 0; j < 4; ++j)
                    acc[i][j] = fmaf(aa[i], bb[j], acc[i][j]);
        }
        __syncthreads();
    }

    #pragma unroll
    for (int i = 0; i < 4; ++i) {
        int r = row0 + (ty << 2) + i;
        if (r >= n) continue;
        #pragma unroll
        for (int j = 0; j < 4; ++j) {
            int c = col0 + (tx << 2) + j;
            if (c >= M) continue;
            float v = acc[i][j];
            if (mode == 0) {
                if (c < split) {
                    if (bias0) v += bias0[c];
                    out0[(size_t)r * w0 + c] = v;
                } else {
                    int cc = c - split;
                    if (bias1) v += bias1[cc];
                    out1[(size_t)r * w1 + cc] = v;
                }
            } else {
                if (bias0) v += bias0[c];
                size_t idx = (size_t)r * 64 + c;
                float an = (acc_in ? acc_in[idx] : 0.f) + c3 * v;
                acc_out[idx] = an;
                t_out[idx] = hbuf[idx] + c1 * v + c2 * an;
            }
        }
    }
}

// ---------------------------------------------------------------------------
// Host-side launcher
// ---------------------------------------------------------------------------

static void hidden_conv(hipStream_t stream, const float* in, float* big0,
                        const int* rowp, const int* es, const float* ep,
                        const float* invd, const float* Bc, const float* bias, int n,
                        int mode, float* out_plain,
                        const float* h, const float* acc_in, float* acc_out,
                        float* t_out, float c1, float c2, float c3) {
    edge_agg64_v4<<<ceil_div(n * 16, 256), 256, 0, stream>>>(in, rowp, es, ep, invd, big0, n);
    dim3 g(ceil_div(n, 64), 1);
    gemm_tiled<<<g, 256, 0, stream>>>(big0, 128, 128, in, 64, Bc, n, 192, 64,
                                      out_plain, 64, bias, nullptr, 0, nullptr, 64, mode,
                                      h, acc_in, acc_out, t_out, c1, c2, c3);
}

extern "C" void kernel_launch(void* const* d_in, const int* in_sizes, int n_in,
                              void* d_out, int out_size, void* d_ws, size_t ws_size,
                              hipStream_t stream) {
    const float* x  = (const float*)d_in[0];
    const float* pE = (const float*)d_in[1];
    const int*   sr = (const int*)d_in[2];
    const int*   ds = (const int*)d_in[3];
    const float* W1 = (const float*)d_in[4];
    const float* R1 = (const float*)d_in[5];
    const float* b1 = (const float*)d_in[6];
    const float* Wa = (const float*)d_in[7];
    const float* Ra = (const float*)d_in[8];
    const float* ba = (const float*)d_in[9];
    const float* Wb = (const float*)d_in[10];
    const float* Rb = (const float*)d_in[11];
    const float* bb = (const float*)d_in[12];
    const float* W2 = (const float*)d_in[13];
    const float* R2 = (const float*)d_in[14];
    const float* b2 = (const float*)d_in[15];
    const int n = in_sizes[0] / 256;
    const int E = in_sizes[2];
    float* out = (float*)d_out;

    char* w = (char*)d_ws;
    auto alloc = [&](size_t bytes) -> void* {
        void* ptr = (void*)w;
        w += (bytes + 255) & ~(size_t)255;
        return ptr;
    };
    int nscan = ceil_div(n, 2048);
    int*   deg  = (int*)alloc((size_t)n * 4);
    int*   fill = (int*)alloc((size_t)n * 4);
    int*   rowp = (int*)alloc((size_t)(n + 1) * 4);
    float* invd = (float*)alloc((size_t)n * 4);
    int*   bsum = (int*)alloc((size_t)256 * 4);
    int*   ei   = (int*)alloc((size_t)E * 4);
    int*   es   = (int*)alloc((size_t)E * 4);
    float* ep   = (float*)alloc((size_t)E * 4);
    float* Bc1  = (float*)alloc((size_t)256 * 192 * 4);
    float* Bca  = (float*)alloc((size_t)192 * 64 * 4);
    float* Bcb  = (float*)alloc((size_t)192 * 64 * 4);
    float* Bc2  = (float*)alloc((size_t)64 * 48 * 4);
    float* big0 = (float*)alloc((size_t)n * 128 * 4);  // yz / agg buffer
    float* big1 = (float*)alloc((size_t)n * 64 * 4);   // base buffer
    float* h    = (float*)alloc((size_t)n * 64 * 4);
    float* u    = (float*)alloc((size_t)n * 64 * 4);
    float* tb   = (float*)alloc((size_t)n * 64 * 4);
    float* acc  = (float*)alloc((size_t)n * 64 * 4);

    hipMemsetAsync(deg, 0, (size_t)n * 4, stream);
    hipMemsetAsync(fill, 0, (size_t)n * 4, stream);

    pack_cat3<<<ceil_div(256 * 192, 256), 256, 0, stream>>>(W1, R1, Bc1, 256, 64);
    pack_cat3<<<ceil_div(64 * 48, 256), 256, 0, stream>>>(W2, R2, Bc2, 64, 16);
    hipMemcpyAsync(Bca, Wa, (size_t)8192 * 4, hipMemcpyDeviceToDevice, stream);
    hipMemcpyAsync(Bca + 8192, Ra, (size_t)4096 * 4, hipMemcpyDeviceToDevice, stream);
    hipMemcpyAsync(Bcb, Wb, (size_t)8192 * 4, hipMemcpyDeviceToDevice, stream);
    hipMemcpyAsync(Bcb + 8192, Rb, (size_t)4096 * 4, hipMemcpyDeviceToDevice, stream);

    hist_kernel<<<ceil_div(E, 256), 256, 0, stream>>>(ds, deg, E);
    scan_blocksum<<<nscan, 256, 0, stream>>>(deg, bsum, n);
    scan_tops<<<1, 256, 0, stream>>>(bsum, nscan);
    scan_final<<<nscan, 256, 0, stream>>>(deg, bsum, rowp, invd, n, E);
    scatter_idx<<<ceil_div(E, 256), 256, 0, stream>>>(ds, rowp, fill, ei, E);
    sort_fill<<<ceil_div(n, 256), 256, 0, stream>>>(rowp, ei, sr, pE, es, ep, n);

    // conv1: transform-first. GEMM x@[W1_0|W1_1|R1] -> yz(big0), base(big1)+b1
    {
        dim3 g(ceil_div(n, 64), 3);
        gemm_tiled<<<g, 256, 0, stream>>>(x, 256, 256, nullptr, 0, Bc1, n, 256, 192,
                                          big0, 128, nullptr, big1, 64, b1, 128, 0,
                                          nullptr, nullptr, nullptr, nullptr, 0.f, 0.f, 0.f);
        edge_tf64_v4<<<ceil_div(n * 16, 256), 256, 0, stream>>>(big0, rowp, es, ep, invd,
                                                                big1, h, n);
    }

    // RK4 over f(y) = conv_b(conv_a(y)), T=3
    // k1
    hidden_conv(stream, h, big0, rowp, es, ep, invd, Bca, ba, n, 0, u,
                nullptr, nullptr, nullptr, nullptr, 0.f, 0.f, 0.f);
    hidden_conv(stream, u, big0, rowp, es, ep, invd, Bcb, bb, n, 1, nullptr,
                h, nullptr, acc, tb, 1.5f, 0.f, 1.f);
    // k2
    hidden_conv(stream, tb, big0, rowp, es, ep, invd, Bca, ba, n, 0, u,
                nullptr, nullptr, nullptr, nullptr, 0.f, 0.f, 0.f);
    hidden_conv(stream, u, big0, rowp, es, ep, invd, Bcb, bb, n, 1, nullptr,
                h, acc, acc, tb, 1.5f, 0.f, 2.f);
    // k3
    hidden_conv(stream, tb, big0, rowp, es, ep, invd, Bca, ba, n, 0, u,
                nullptr, nullptr, nullptr, nullptr, 0.f, 0.f, 0.f);
    hidden_conv(stream, u, big0, rowp, es, ep, invd, Bcb, bb, n, 1, nullptr,
                h, acc, acc, tb, 3.f, 0.f, 2.f);
    // k4: t_out becomes h_new = h + 0.5*(k1+2k2+2k3+k4)
    hidden_conv(stream, tb, big0, rowp, es, ep, invd, Bca, ba, n, 0, u,
                nullptr, nullptr, nullptr, nullptr, 0.f, 0.f, 0.f);
    hidden_conv(stream, u, big0, rowp, es, ep, invd, Bcb, bb, n, 1, nullptr,
                h, acc, acc, tb, 0.f, 0.5f, 1.f);

    // conv2: transform-first. GEMM h_new@[W2_0|W2_1|R2] -> yz2(big0,w=32), base2(big1,w=16)+b2
    {
        dim3 g(ceil_div(n, 64), 1);
        gemm_tiled<<<g, 256, 0, stream>>>(tb, 64, 64, nullptr, 0, Bc2, n, 64, 48,
                                          big0, 32, nullptr, big1, 16, b2, 32, 0,
                                          nullptr, nullptr, nullptr, nullptr, 0.f, 0.f, 0.f);
        edge_tf16_lsm<<<ceil_div(n * 16, 256), 256, 0, stream>>>(big0, rowp, es, ep, invd,
                                                                 big1, out, n);
    }
}